// Round 2
// baseline (1010.488 us; speedup 1.0000x reference)
//
#include <hip/hip_runtime.h>
#include <hip/hip_bf16.h>
#include <math.h>

#define Mrows 4096      // B*T
#define Kdim  256       // F
#define Ncols 16384     // G*V
#define Vsz   8192

typedef __attribute__((ext_vector_type(8))) short bf16x8;
typedef __attribute__((ext_vector_type(4))) float f32x4;

// async global->LDS, 16 bytes per lane (dest must be linear: base + lane*16)
#define GLD16(ldsp, gp) __builtin_amdgcn_global_load_lds(                          \
    (const __attribute__((address_space(1))) unsigned int*)(gp),                   \
    (__attribute__((address_space(3))) unsigned int*)(ldsp), 16, 0, 0)

// ---------------- split fp32 -> bf16 (hi, lo) ---------------------------------
__global__ __launch_bounds__(256) void split_bf16(const float* __restrict__ src,
                                                  __hip_bfloat16* __restrict__ hi,
                                                  __hip_bfloat16* __restrict__ lo) {
    const int i = blockIdx.x * 256 + threadIdx.x;
    const float v = src[i];
    const __hip_bfloat16 h = __float2bfloat16(v);
    const float hf = __bfloat162float(h);
    hi[i] = h;
    lo[i] = __float2bfloat16(v - hf);
}

// ---------------- GEMM: hid[m][n] = sum_k A[m][k]*B[n][k] + bias[n] -----------
// split-bf16 3-term MFMA (ah*bh + ah*bl + al*bh), 128x128 tile, BK=32
// staging via global_load_lds width=16; per-j B fragments to cut VGPR
__global__ __launch_bounds__(256, 3) void gemm_mfma(const __hip_bfloat16* __restrict__ Ahi,
                                                    const __hip_bfloat16* __restrict__ Alo,
                                                    const __hip_bfloat16* __restrict__ Bhi,
                                                    const __hip_bfloat16* __restrict__ Blo,
                                                    const float* __restrict__ bias,
                                                    float* __restrict__ hid, int r0) {
    __shared__ unsigned short Ah[128 * 32], Al[128 * 32], Bh[128 * 32], Bl[128 * 32];
    const int tid = threadIdx.x;
    const int lane = tid & 63;
    const int wave = tid >> 6;
    const int bm = blockIdx.x * 128;            // chunk-local m tile
    const int bn = blockIdx.y * 128;            // n tile
    const int wm = (wave & 1) * 64;
    const int wn = (wave >> 1) * 64;
    const int lm = lane & 15;                   // row within 16
    const int kq = (lane >> 4) * 8;             // k octet

    f32x4 acc[4][4];
#pragma unroll
    for (int i = 0; i < 4; ++i)
#pragma unroll
        for (int j = 0; j < 4; ++j) acc[i][j] = (f32x4){0.f, 0.f, 0.f, 0.f};

    for (int k0 = 0; k0 < Kdim; k0 += 32) {
        __syncthreads();                        // previous iter's ds_reads done
#pragma unroll
        for (int t = 0; t < 2; ++t) {
            const int c = tid + t * 256;        // 0..511; LDS dest = c*16 bytes (linear)
            const int row = c >> 2;             // 0..127
            const int ko = (c & 3) * 8;         // 0,8,16,24
            const size_t ga = (size_t)(r0 + bm + row) * Kdim + k0 + ko;
            const size_t gb = (size_t)(bn + row) * Kdim + k0 + ko;
            GLD16(&Ah[c * 8], Ahi + ga);
            GLD16(&Al[c * 8], Alo + ga);
            GLD16(&Bh[c * 8], Bhi + gb);
            GLD16(&Bl[c * 8], Blo + gb);
        }
        __syncthreads();                        // compiler drains vmcnt before barrier

        bf16x8 ah[4], al[4];
#pragma unroll
        for (int i = 0; i < 4; ++i) {
            ah[i] = *(const bf16x8*)&Ah[(wm + i * 16 + lm) * 32 + kq];
            al[i] = *(const bf16x8*)&Al[(wm + i * 16 + lm) * 32 + kq];
        }
#pragma unroll
        for (int j = 0; j < 4; ++j) {
            const bf16x8 bh = *(const bf16x8*)&Bh[(wn + j * 16 + lm) * 32 + kq];
            const bf16x8 bl = *(const bf16x8*)&Bl[(wn + j * 16 + lm) * 32 + kq];
#pragma unroll
            for (int i = 0; i < 4; ++i) {
                acc[i][j] = __builtin_amdgcn_mfma_f32_16x16x32_bf16(ah[i], bh, acc[i][j], 0, 0, 0);
                acc[i][j] = __builtin_amdgcn_mfma_f32_16x16x32_bf16(ah[i], bl, acc[i][j], 0, 0, 0);
                acc[i][j] = __builtin_amdgcn_mfma_f32_16x16x32_bf16(al[i], bh, acc[i][j], 0, 0, 0);
            }
        }
    }

    // epilogue: C/D layout col=lane&15, row=(lane>>4)*4+reg  [m89/m91 verified]
    const int rbase = (lane >> 4) * 4;
#pragma unroll
    for (int j = 0; j < 4; ++j) {
        const int n = bn + wn + j * 16 + lm;
        const float bj = bias[n];
#pragma unroll
        for (int i = 0; i < 4; ++i) {
            const int m0 = bm + wm + i * 16 + rbase;
#pragma unroll
            for (int r2 = 0; r2 < 4; ++r2)
                hid[(size_t)(m0 + r2) * Ncols + n] = acc[i][j][r2] + bj;
        }
    }
}

// ---------------- Phase 2: softmax x2, argmax, codevectors, marginal ----------
// 512 threads, 16 elems/thread, interleaved mapping v = k*512 + tid:
//   - emb gather: dense 32 B/lane stride (perfect coalescing)
//   - u/hid: coalesced scalar loads (4 B/lane)
// hv + marg kept in registers: hid read ONCE, no marg LDS
__global__ __launch_bounds__(512, 4) void phase2(const float* __restrict__ hid,
                                                 const float* __restrict__ u,
                                                 const float* __restrict__ emb,
                                                 const int* __restrict__ mask,
                                                 float* __restrict__ marginal,
                                                 float* __restrict__ out,
                                                 int r0) {
    const int g = blockIdx.y;
    const int n0 = r0 + blockIdx.x * 8;
    const int tid = threadIdx.x;
    const int lane = tid & 63;
    const int wid = tid >> 6;

    __shared__ float sv1[8]; __shared__ int si1[8]; __shared__ float sv2[8];
    __shared__ float ss1[8], ss2[8], scv[8][8];

    const float* embg = emb + (size_t)g * Vsz * 8;
    float marg[16];
#pragma unroll
    for (int k = 0; k < 16; ++k) marg[k] = 0.f;
    float lg[16], hv[16];

    for (int r = 0; r < 8; ++r) {
        const int n = n0 + r;
        const float* hrow = hid + (size_t)(n - r0) * Ncols + (size_t)g * Vsz;
        const float* urow = u + ((size_t)n * 2 + g) * Vsz;

        // ---- pass A: noisy logits + running maxes (hid read once, kept in regs) ----
        float mx1 = -INFINITY, mx2 = -INFINITY;
        int amax = 0;
#pragma unroll
        for (int k = 0; k < 16; ++k) {
            const int v = (k << 9) + tid;
            const float h = hrow[v];
            const float uraw = urow[v];
            float uu = fminf(fmaxf(uraw, 1.17549435e-38f), 1.0f);
            const float d = uu - 1.0f;
            // -log(u) via log1p Taylor for u>0.8 (hw log abs-error zone), else native
            float q = 1.0f / 9.0f;
            q = fmaf(q, d, -0.125f);
            q = fmaf(q, d, 1.0f / 7.0f);
            q = fmaf(q, d, -1.0f / 6.0f);
            q = fmaf(q, d, 0.2f);
            q = fmaf(q, d, -0.25f);
            q = fmaf(q, d, 1.0f / 3.0f);
            q = fmaf(q, d, -0.5f);
            q = fmaf(q, d, 1.0f);
            const float inner = (d > -0.2f) ? (-d) * q : -__logf(uu);
            const float l = h - __logf(inner);      // h + gumbel
            lg[k] = l;
            hv[k] = h;
            if (l > mx1) { mx1 = l; amax = v; }
            mx2 = fmaxf(mx2, h);
        }
#pragma unroll
        for (int off = 32; off > 0; off >>= 1) {
            const float ov = __shfl_down(mx1, off);
            const int oi = __shfl_down(amax, off);
            if (ov > mx1 || (ov == mx1 && oi < amax)) { mx1 = ov; amax = oi; }
            mx2 = fmaxf(mx2, __shfl_down(mx2, off));
        }
        if (lane == 0) { sv1[wid] = mx1; si1[wid] = amax; sv2[wid] = mx2; }
        __syncthreads();
        if (tid == 0) {
            float bv = sv1[0]; int bi = si1[0]; float b2 = sv2[0];
            for (int w2 = 1; w2 < 8; ++w2) {
                if (sv1[w2] > bv || (sv1[w2] == bv && si1[w2] < bi)) { bv = sv1[w2]; bi = si1[w2]; }
                b2 = fmaxf(b2, sv2[w2]);
            }
            sv1[0] = bv; si1[0] = bi; sv2[0] = b2;
        }
        __syncthreads();
        const float M1 = sv1[0];
        const float M2 = sv2[0];
        const int AMAX = si1[0];

        // ---- pass B: sums + codevectors (emb dense gather); lg[] -> clean exps ----
        float s1 = 0.f, s2 = 0.f;
        float cv[8];
#pragma unroll
        for (int d2 = 0; d2 < 8; ++d2) cv[d2] = 0.f;
#pragma unroll
        for (int k = 0; k < 16; ++k) {
            const int v = (k << 9) + tid;
            const float p = __expf(lg[k] - M1);
            s1 += p;
            const float4 e0 = *(const float4*)(embg + (size_t)v * 8);
            const float4 e1 = *(const float4*)(embg + (size_t)v * 8 + 4);
            cv[0] = fmaf(p, e0.x, cv[0]); cv[1] = fmaf(p, e0.y, cv[1]);
            cv[2] = fmaf(p, e0.z, cv[2]); cv[3] = fmaf(p, e0.w, cv[3]);
            cv[4] = fmaf(p, e1.x, cv[4]); cv[5] = fmaf(p, e1.y, cv[5]);
            cv[6] = fmaf(p, e1.z, cv[6]); cv[7] = fmaf(p, e1.w, cv[7]);
            const float qq = __expf(hv[k] - M2);
            s2 += qq;
            lg[k] = qq;
        }
#pragma unroll
        for (int off = 32; off > 0; off >>= 1) {
            s1 += __shfl_down(s1, off);
            s2 += __shfl_down(s2, off);
        }
#pragma unroll
        for (int d2 = 0; d2 < 8; ++d2)
#pragma unroll
            for (int off = 32; off > 0; off >>= 1) cv[d2] += __shfl_down(cv[d2], off);
        if (lane == 0) {
            ss1[wid] = s1; ss2[wid] = s2;
#pragma unroll
            for (int d2 = 0; d2 < 8; ++d2) scv[wid][d2] = cv[d2];
        }
        __syncthreads();
        if (tid == 0) {
            float a = 0.f, b = 0.f;
            for (int w2 = 0; w2 < 8; ++w2) { a += ss1[w2]; b += ss2[w2]; }
            ss1[0] = a; ss2[0] = b;
        }
        __syncthreads();
        const float S1 = ss1[0];
        const float S2 = ss2[0];
        if (tid < 8) {
            float c = 0.f;
#pragma unroll
            for (int w2 = 0; w2 < 8; ++w2) c += scv[w2][tid];
            out[(size_t)n * 16 + g * 8 + tid] = c / S1;
        }
        if (tid == 8) out[65537 + (size_t)n * 2 + g] = (float)AMAX;

        if (mask[n] != 0) {
            const float invS2 = 1.0f / S2;
#pragma unroll
            for (int k = 0; k < 16; ++k)
                marg[k] = fmaf(lg[k], invS2, marg[k]);
        }
        // next row's shared-array writes are gated by its own barriers
    }
#pragma unroll
    for (int k = 0; k < 16; ++k)
        atomicAdd(&marginal[g * Vsz + (k << 9) + tid], marg[k]);
}

// ---------------- Perplexity --------------------------------------------------
__global__ __launch_bounds__(256) void ppl_kernel(const float* __restrict__ marginal,
                                                  const int* __restrict__ mask,
                                                  float* __restrict__ out) {
    const int tid = threadIdx.x;
    const int lane = tid & 63;
    const int wid = tid >> 6;
    __shared__ float red[4];
    __shared__ int redi[4];

    int ms = 0;
    for (int i = tid; i < Mrows; i += 256) ms += mask[i];
#pragma unroll
    for (int off = 32; off > 0; off >>= 1) ms += __shfl_down(ms, off);
    if (lane == 0) redi[wid] = ms;
    __syncthreads();
    const float inv = 1.0f / (float)(redi[0] + redi[1] + redi[2] + redi[3]);

    float ppl = 0.f;
    for (int g = 0; g < 2; ++g) {
        float part = 0.f;
        for (int v = tid; v < Vsz; v += 256) {
            const float m = marginal[g * Vsz + v] * inv;
            part += m * logf(m + 1e-7f);
        }
#pragma unroll
        for (int off = 32; off > 0; off >>= 1) part += __shfl_down(part, off);
        __syncthreads();
        if (lane == 0) red[wid] = part;
        __syncthreads();
        if (tid == 0) ppl += __expf(-(red[0] + red[1] + red[2] + red[3]));
        __syncthreads();
    }
    if (tid == 0) out[65536] = ppl;
}

// ---------------- Launch ------------------------------------------------------
extern "C" void kernel_launch(void* const* d_in, const int* in_sizes, int n_in,
                              void* d_out, int out_size, void* d_ws, size_t ws_size,
                              hipStream_t stream) {
    const float* x    = (const float*)d_in[0];
    const float* u    = (const float*)d_in[1];
    const float* emb  = (const float*)d_in[2];
    const float* w    = (const float*)d_in[3];
    const float* bias = (const float*)d_in[4];
    const int*   mask = (const int*)d_in[5];
    float* out = (float*)d_out;

    char* base = (char*)d_ws;
    float* marginal = (float*)base;                                    // 64 KB
    __hip_bfloat16* Ahi = (__hip_bfloat16*)(base + 65536);             // 2 MB
    __hip_bfloat16* Alo = Ahi + 1048576;                               // 2 MB
    __hip_bfloat16* Bhi = Alo + 1048576;                               // 8 MB
    __hip_bfloat16* Blo = Bhi + 4194304;                               // 8 MB
    const size_t hid_off = 65536 + 4194304 + 16777216;                 // 21037056
    float* hid = (float*)(base + hid_off);

    size_t cap_rows = (ws_size > hid_off) ? (ws_size - hid_off) / ((size_t)Ncols * 4) : 0;
    int cr = (cap_rows >= Mrows) ? Mrows : (int)((cap_rows / 128) * 128);
    if (cr < 128) cr = 128;
    // chunk so the hid slice (cr*64KB) stays L3-resident between GEMM and phase2:
    // cr=2048 -> 128 MB << 256 MB L3; phase2 grid (256,2)=512 blocks = full fill
    if (cr > 2048) cr = 2048;

    hipMemsetAsync(marginal, 0, 65536, stream);
    split_bf16<<<4096, 256, 0, stream>>>(x, Ahi, Alo);      // 1M elems
    split_bf16<<<16384, 256, 0, stream>>>(w, Bhi, Blo);     // 4M elems

    for (int r0 = 0; r0 < Mrows; r0 += cr) {
        const int rows = (Mrows - r0 < cr) ? (Mrows - r0) : cr;
        dim3 gg(rows / 128, Ncols / 128);
        gemm_mfma<<<gg, 256, 0, stream>>>(Ahi, Alo, Bhi, Blo, bias, hid, r0);
        dim3 pg(rows / 8, 2);
        phase2<<<pg, 512, 0, stream>>>(hid, u, emb, mask, marginal, out, r0);
    }
    ppl_kernel<<<1, 256, 0, stream>>>(marginal, mask, out);
}

// Round 3
// 913.313 us; speedup vs baseline: 1.1064x; 1.1064x over previous
//
#include <hip/hip_runtime.h>
#include <hip/hip_bf16.h>
#include <math.h>

#define Mrows 4096      // B*T
#define Kdim  256       // F
#define Ncols 16384     // G*V
#define Vsz   8192
#define ROWS  16        // rows per phase2 block

typedef __attribute__((ext_vector_type(8))) short bf16x8;
typedef __attribute__((ext_vector_type(4))) float f32x4;

// async global->LDS, 16 bytes per lane (dest must be linear: base + lane*16)
#define GLD16(ldsp, gp) __builtin_amdgcn_global_load_lds(                          \
    (const __attribute__((address_space(1))) unsigned int*)(gp),                   \
    (__attribute__((address_space(3))) unsigned int*)(ldsp), 16, 0, 0)

// raw barrier: LDS-visibility only, leaves global (prefetch) loads in flight
#define BARRIER_LDS() do {                                                         \
    asm volatile("s_waitcnt lgkmcnt(0)" ::: "memory");                             \
    __builtin_amdgcn_s_barrier();                                                  \
} while (0)

// ---------------- split fp32 -> bf16 (hi, lo) ---------------------------------
__global__ __launch_bounds__(256) void split_bf16(const float* __restrict__ src,
                                                  __hip_bfloat16* __restrict__ hi,
                                                  __hip_bfloat16* __restrict__ lo) {
    const int i = blockIdx.x * 256 + threadIdx.x;
    const float v = src[i];
    const __hip_bfloat16 h = __float2bfloat16(v);
    const float hf = __bfloat162float(h);
    hi[i] = h;
    lo[i] = __float2bfloat16(v - hf);
}

// ---------------- GEMM: hid[m][n] = sum_k A[m][k]*B[n][k] + bias[n] -----------
// split-bf16 3-term MFMA, 128x128 tile, BK=32, global_load_lds staging.
// LDS slot-swizzle (rule 21): linear dest, source octet ^= row&3, read ^= lm&3
// -> fragment ds_read_b128 goes 8-way-conflict -> 2-way (free).
__global__ __launch_bounds__(256, 3) void gemm_mfma(const __hip_bfloat16* __restrict__ Ahi,
                                                    const __hip_bfloat16* __restrict__ Alo,
                                                    const __hip_bfloat16* __restrict__ Bhi,
                                                    const __hip_bfloat16* __restrict__ Blo,
                                                    const float* __restrict__ bias,
                                                    float* __restrict__ hid, int r0) {
    __shared__ unsigned short Ah[128 * 32], Al[128 * 32], Bh[128 * 32], Bl[128 * 32];
    const int tid = threadIdx.x;
    const int lane = tid & 63;
    const int wave = tid >> 6;

    // bijective XCD tile swizzle: nwg = gx*gy is always a multiple of 8 here
    const int gx = gridDim.x;
    int fid = blockIdx.y * gx + blockIdx.x;
    const int per = (gx * gridDim.y) >> 3;
    fid = (fid & 7) * per + (fid >> 3);
    const int bm = (fid % gx) * 128;            // chunk-local m tile
    const int bn = (fid / gx) * 128;            // n tile

    const int wm = (wave & 1) * 64;
    const int wn = (wave >> 1) * 64;
    const int lm = lane & 15;                   // row within 16
    const int sl = (((lane >> 4) ^ (lm & 3)) << 3);   // swizzled k-octet (shorts)

    f32x4 acc[4][4];
#pragma unroll
    for (int i = 0; i < 4; ++i)
#pragma unroll
        for (int j = 0; j < 4; ++j) acc[i][j] = (f32x4){0.f, 0.f, 0.f, 0.f};

    for (int k0 = 0; k0 < Kdim; k0 += 32) {
        __syncthreads();
#pragma unroll
        for (int t = 0; t < 2; ++t) {
            const int c = tid + t * 256;        // 0..511; LDS dest byte = c*16 (linear)
            const int row = c >> 2;             // 0..127
            const int ko = (((c & 3) ^ (row & 3)) << 3);   // pre-swizzled source octet
            const size_t ga = (size_t)(r0 + bm + row) * Kdim + k0 + ko;
            const size_t gb = (size_t)(bn + row) * Kdim + k0 + ko;
            GLD16(&Ah[c * 8], Ahi + ga);
            GLD16(&Al[c * 8], Alo + ga);
            GLD16(&Bh[c * 8], Bhi + gb);
            GLD16(&Bl[c * 8], Blo + gb);
        }
        __syncthreads();                        // drains vmcnt (staging complete)

        bf16x8 ah[4], al[4];
#pragma unroll
        for (int i = 0; i < 4; ++i) {
            ah[i] = *(const bf16x8*)&Ah[(wm + i * 16 + lm) * 32 + sl];
            al[i] = *(const bf16x8*)&Al[(wm + i * 16 + lm) * 32 + sl];
        }
#pragma unroll
        for (int j = 0; j < 4; ++j) {
            const bf16x8 bh = *(const bf16x8*)&Bh[(wn + j * 16 + lm) * 32 + sl];
            const bf16x8 bl = *(const bf16x8*)&Bl[(wn + j * 16 + lm) * 32 + sl];
#pragma unroll
            for (int i = 0; i < 4; ++i) {
                acc[i][j] = __builtin_amdgcn_mfma_f32_16x16x32_bf16(ah[i], bh, acc[i][j], 0, 0, 0);
                acc[i][j] = __builtin_amdgcn_mfma_f32_16x16x32_bf16(ah[i], bl, acc[i][j], 0, 0, 0);
                acc[i][j] = __builtin_amdgcn_mfma_f32_16x16x32_bf16(al[i], bh, acc[i][j], 0, 0, 0);
            }
        }
    }

    // epilogue: C/D layout col=lane&15, row=(lane>>4)*4+reg  [m89/m91 verified]
    const int rbase = (lane >> 4) * 4;
#pragma unroll
    for (int j = 0; j < 4; ++j) {
        const int n = bn + wn + j * 16 + lm;
        const float bj = bias[n];
#pragma unroll
        for (int i = 0; i < 4; ++i) {
            const int m0 = bm + wm + i * 16 + rbase;
#pragma unroll
            for (int r2 = 0; r2 < 4; ++r2)
                hid[(size_t)(m0 + r2) * Ncols + n] = acc[i][j][r2] + bj;
        }
    }
}

// ---------------- Phase 2: softmax x2, argmax, codevectors, marginal ----------
// 1024 threads, 8 elems/thread (v = k*1024 + tid), 16 rows/block.
// Cross-row register prefetch of hid/u survives the raw (lgkmcnt-only) barriers.
// Clean softmax via qq = p * inner * exp(M1-M2): no second exp, no hid re-read.
// Marginal: per-block partial stored non-atomically; reduced by reduce_marg.
__global__ __launch_bounds__(1024, 4) void phase2(const float* __restrict__ hid,
                                                  const float* __restrict__ u,
                                                  const float* __restrict__ emb,
                                                  const int* __restrict__ mask,
                                                  float* __restrict__ part,
                                                  float* __restrict__ out,
                                                  int r0) {
    const int tid = threadIdx.x;
    const int lane = tid & 63;
    const int wid = tid >> 6;

    // bijective XCD swizzle over (g, bx): nbx is a multiple of 8 (rows mult of 128)
    const int nbx = gridDim.x;
    int fid = blockIdx.y * nbx + blockIdx.x;
    const int per = (nbx * 2) >> 3;
    fid = (fid & 7) * per + (fid >> 3);
    const int g = fid / nbx;
    const int bx = fid % nbx;

    const int n0 = r0 + bx * ROWS;
    const int pb = r0 / ROWS + bx;            // global partial index

    __shared__ float sv1[16]; __shared__ int si1[16]; __shared__ float sv2[16];
    __shared__ float ss1[16], ss2[16], scv[16][8];

    const float* embg = emb + (size_t)g * Vsz * 8;
    float marg[8];
#pragma unroll
    for (int k = 0; k < 8; ++k) marg[k] = 0.f;
    float lg[8], h0[8], u0[8], h1[8], u1[8];

    {   // preload row 0
        const float* hr = hid + (size_t)(n0 - r0) * Ncols + (size_t)g * Vsz;
        const float* ur = u + ((size_t)n0 * 2 + g) * Vsz;
#pragma unroll
        for (int k = 0; k < 8; ++k) { h0[k] = hr[(k << 10) + tid]; u0[k] = ur[(k << 10) + tid]; }
    }

#define ROWSTEP(CH, CU, NH, NU, r) {                                               \
    const int n = n0 + (r);                                                        \
    if ((r) + 1 < ROWS) {   /* prefetch next row; stays in flight across BARs */   \
        const float* hN = hid + (size_t)(n + 1 - r0) * Ncols + (size_t)g * Vsz;    \
        const float* uN = u + ((size_t)(n + 1) * 2 + g) * Vsz;                     \
        _Pragma("unroll")                                                          \
        for (int k = 0; k < 8; ++k) {                                              \
            NH[k] = hN[(k << 10) + tid]; NU[k] = uN[(k << 10) + tid];              \
        }                                                                          \
    }                                                                              \
    const int rmask = mask[n];                                                     \
    /* pass A: noisy logits + maxes; CH[k] overwritten with inner = exp(-gum) */   \
    float mx1 = -INFINITY, mx2 = -INFINITY;                                        \
    int amax = 0;                                                                  \
    _Pragma("unroll")                                                              \
    for (int k = 0; k < 8; ++k) {                                                  \
        const float h = CH[k];                                                     \
        float uu = fminf(fmaxf(CU[k], 1.17549435e-38f), 1.0f);                     \
        const float d = uu - 1.0f;                                                 \
        float q = 1.0f / 9.0f;                                                     \
        q = fmaf(q, d, -0.125f);                                                   \
        q = fmaf(q, d, 1.0f / 7.0f);                                               \
        q = fmaf(q, d, -1.0f / 6.0f);                                              \
        q = fmaf(q, d, 0.2f);                                                      \
        q = fmaf(q, d, -0.25f);                                                    \
        q = fmaf(q, d, 1.0f / 3.0f);                                               \
        q = fmaf(q, d, -0.5f);                                                     \
        q = fmaf(q, d, 1.0f);                                                      \
        const float inner = (d > -0.2f) ? (-d) * q : -__logf(uu);                  \
        const float l = h - __logf(inner);                                         \
        lg[k] = l;                                                                 \
        CH[k] = inner;                                                             \
        if (l > mx1) { mx1 = l; amax = (k << 10) + tid; }                          \
        mx2 = fmaxf(mx2, h);                                                       \
    }                                                                              \
    _Pragma("unroll")                                                              \
    for (int off = 32; off > 0; off >>= 1) {                                       \
        const float ov = __shfl_down(mx1, off);                                    \
        const int oi = __shfl_down(amax, off);                                     \
        if (ov > mx1 || (ov == mx1 && oi < amax)) { mx1 = ov; amax = oi; }         \
        mx2 = fmaxf(mx2, __shfl_down(mx2, off));                                   \
    }                                                                              \
    if (lane == 0) { sv1[wid] = mx1; si1[wid] = amax; sv2[wid] = mx2; }            \
    BARRIER_LDS();                                                                 \
    float M1 = sv1[0]; int AMAX = si1[0]; float M2 = sv2[0];                       \
    _Pragma("unroll")                                                              \
    for (int w2 = 1; w2 < 16; ++w2) {                                              \
        const float a = sv1[w2]; const int b = si1[w2];                            \
        if (a > M1 || (a == M1 && b < AMAX)) { M1 = a; AMAX = b; }                 \
        M2 = fmaxf(M2, sv2[w2]);                                                   \
    }                                                                              \
    const float Cq = __expf(M1 - M2);                                              \
    /* pass B: sums + codevectors; lg[] -> clean exp terms */                      \
    float s1 = 0.f, s2 = 0.f;                                                      \
    float cv[8];                                                                   \
    _Pragma("unroll")                                                              \
    for (int d2 = 0; d2 < 8; ++d2) cv[d2] = 0.f;                                   \
    _Pragma("unroll")                                                              \
    for (int k = 0; k < 8; ++k) {                                                  \
        const int v = (k << 10) + tid;                                             \
        const float p = __expf(lg[k] - M1);                                        \
        s1 += p;                                                                   \
        const float4 e0 = *(const float4*)(embg + (size_t)v * 8);                  \
        const float4 e1 = *(const float4*)(embg + (size_t)v * 8 + 4);              \
        cv[0] = fmaf(p, e0.x, cv[0]); cv[1] = fmaf(p, e0.y, cv[1]);                \
        cv[2] = fmaf(p, e0.z, cv[2]); cv[3] = fmaf(p, e0.w, cv[3]);                \
        cv[4] = fmaf(p, e1.x, cv[4]); cv[5] = fmaf(p, e1.y, cv[5]);                \
        cv[6] = fmaf(p, e1.z, cv[6]); cv[7] = fmaf(p, e1.w, cv[7]);                \
        const float qq = p * CH[k] * Cq;                                           \
        s2 += qq;                                                                  \
        lg[k] = qq;                                                                \
    }                                                                              \
    _Pragma("unroll")                                                              \
    for (int off = 32; off > 0; off >>= 1) {                                       \
        s1 += __shfl_down(s1, off);                                                \
        s2 += __shfl_down(s2, off);                                                \
    }                                                                              \
    _Pragma("unroll")                                                              \
    for (int d2 = 0; d2 < 8; ++d2)                                                 \
        _Pragma("unroll")                                                          \
        for (int off = 32; off > 0; off >>= 1) cv[d2] += __shfl_down(cv[d2], off); \
    if (lane == 0) {                                                               \
        ss1[wid] = s1; ss2[wid] = s2;                                              \
        _Pragma("unroll")                                                          \
        for (int d2 = 0; d2 < 8; ++d2) scv[wid][d2] = cv[d2];                      \
    }                                                                              \
    BARRIER_LDS();                                                                 \
    float S1 = 0.f, S2 = 0.f;                                                      \
    _Pragma("unroll")                                                              \
    for (int w2 = 0; w2 < 16; ++w2) { S1 += ss1[w2]; S2 += ss2[w2]; }              \
    if (tid < 8) {                                                                 \
        float c = 0.f;                                                             \
        _Pragma("unroll")                                                          \
        for (int w2 = 0; w2 < 16; ++w2) c += scv[w2][tid];                         \
        out[(size_t)n * 16 + g * 8 + tid] = c / S1;                                \
    }                                                                              \
    if (tid == 8) out[65537 + (size_t)n * 2 + g] = (float)AMAX;                    \
    if (rmask != 0) {                                                              \
        const float invS2 = 1.0f / S2;                                             \
        _Pragma("unroll")                                                          \
        for (int k = 0; k < 8; ++k) marg[k] = fmaf(lg[k], invS2, marg[k]);         \
    }                                                                              \
}

    for (int r = 0; r < ROWS; r += 2) {
        ROWSTEP(h0, u0, h1, u1, r)
        ROWSTEP(h1, u1, h0, u0, r + 1)
    }
#undef ROWSTEP

    // non-atomic partial store (coalesced)
    float* pr = part + ((size_t)g * (Mrows / ROWS) + pb) * Vsz;
#pragma unroll
    for (int k = 0; k < 8; ++k) pr[(k << 10) + tid] = marg[k];
}

// ---------------- marginal reduce: sum 256 block-partials per (g,v) -----------
__global__ __launch_bounds__(256) void reduce_marg(const float* __restrict__ part,
                                                   float* __restrict__ marginal) {
    const int g = blockIdx.y;
    const int v = blockIdx.x * 256 + threadIdx.x;
    const float* p = part + (size_t)g * (Mrows / ROWS) * Vsz + v;
    float s = 0.f;
    for (int b = 0; b < Mrows / ROWS; ++b) s += p[(size_t)b * Vsz];
    marginal[g * Vsz + v] = s;
}

// ---------------- Perplexity --------------------------------------------------
__global__ __launch_bounds__(256) void ppl_kernel(const float* __restrict__ marginal,
                                                  const int* __restrict__ mask,
                                                  float* __restrict__ out) {
    const int tid = threadIdx.x;
    const int lane = tid & 63;
    const int wid = tid >> 6;
    __shared__ float red[4];
    __shared__ int redi[4];

    int ms = 0;
    for (int i = tid; i < Mrows; i += 256) ms += mask[i];
#pragma unroll
    for (int off = 32; off > 0; off >>= 1) ms += __shfl_down(ms, off);
    if (lane == 0) redi[wid] = ms;
    __syncthreads();
    const float inv = 1.0f / (float)(redi[0] + redi[1] + redi[2] + redi[3]);

    float ppl = 0.f;
    for (int g = 0; g < 2; ++g) {
        float part = 0.f;
        for (int v = tid; v < Vsz; v += 256) {
            const float m = marginal[g * Vsz + v] * inv;
            part += m * logf(m + 1e-7f);
        }
#pragma unroll
        for (int off = 32; off > 0; off >>= 1) part += __shfl_down(part, off);
        __syncthreads();
        if (lane == 0) red[wid] = part;
        __syncthreads();
        if (tid == 0) ppl += __expf(-(red[0] + red[1] + red[2] + red[3]));
        __syncthreads();
    }
    if (tid == 0) out[65536] = ppl;
}

// ---------------- Launch ------------------------------------------------------
extern "C" void kernel_launch(void* const* d_in, const int* in_sizes, int n_in,
                              void* d_out, int out_size, void* d_ws, size_t ws_size,
                              hipStream_t stream) {
    const float* x    = (const float*)d_in[0];
    const float* u    = (const float*)d_in[1];
    const float* emb  = (const float*)d_in[2];
    const float* w    = (const float*)d_in[3];
    const float* bias = (const float*)d_in[4];
    const int*   mask = (const int*)d_in[5];
    float* out = (float*)d_out;

    char* base = (char*)d_ws;
    float* marginal = (float*)base;                                    // 64 KB
    float* part = (float*)(base + 65536);                              // 16 MB
    __hip_bfloat16* Ahi = (__hip_bfloat16*)(base + 65536 + 16777216);  // 2 MB
    __hip_bfloat16* Alo = Ahi + 1048576;                               // 2 MB
    __hip_bfloat16* Bhi = Alo + 1048576;                               // 8 MB
    __hip_bfloat16* Blo = Bhi + 4194304;                               // 8 MB
    const size_t hid_off = 65536 + 16777216 + 4194304 + 16777216;      // ~36 MB
    float* hid = (float*)(base + hid_off);

    size_t cap_rows = (ws_size > hid_off) ? (ws_size - hid_off) / ((size_t)Ncols * 4) : 0;
    int cr = (cap_rows >= Mrows) ? Mrows : (int)((cap_rows / 128) * 128);
    if (cr < 128) cr = 128;

    split_bf16<<<4096, 256, 0, stream>>>(x, Ahi, Alo);      // 1M elems
    split_bf16<<<16384, 256, 0, stream>>>(w, Bhi, Blo);     // 4M elems

    for (int r0 = 0; r0 < Mrows; r0 += cr) {
        const int rows = (Mrows - r0 < cr) ? (Mrows - r0) : cr;
        dim3 gg(rows / 128, Ncols / 128);
        gemm_mfma<<<gg, 256, 0, stream>>>(Ahi, Alo, Bhi, Blo, bias, hid, r0);
        dim3 pg(rows / ROWS, 2);
        phase2<<<pg, 1024, 0, stream>>>(hid, u, emb, mask, part, out, r0);
    }
    reduce_marg<<<dim3(Vsz / 256, 2), 256, 0, stream>>>(part, marginal);
    ppl_kernel<<<1, 256, 0, stream>>>(marginal, mask, out);
}

// Round 4
// 725.638 us; speedup vs baseline: 1.3926x; 1.2586x over previous
//
#include <hip/hip_runtime.h>
#include <hip/hip_bf16.h>
#include <math.h>

#define Mrows 4096      // B*T
#define Kdim  256       // F
#define Ncols 16384     // G*V
#define Vsz   8192
#define NSEG  16        // marg_acc row segments

typedef __attribute__((ext_vector_type(8))) short bf16x8;
typedef __attribute__((ext_vector_type(4))) float f32x4;

// async global->LDS, 16 bytes per lane (dest must be linear: base + lane*16)
#define GLD16(ldsp, gp) __builtin_amdgcn_global_load_lds(                          \
    (const __attribute__((address_space(1))) unsigned int*)(gp),                   \
    (__attribute__((address_space(3))) unsigned int*)(ldsp), 16, 0, 0)

// ---------------- split fp32 -> bf16 (hi, lo) ---------------------------------
__global__ __launch_bounds__(256) void split_bf16(const float* __restrict__ src,
                                                  __hip_bfloat16* __restrict__ hi,
                                                  __hip_bfloat16* __restrict__ lo) {
    const int i = blockIdx.x * 256 + threadIdx.x;
    const float v = src[i];
    const __hip_bfloat16 h = __float2bfloat16(v);
    const float hf = __bfloat162float(h);
    hi[i] = h;
    lo[i] = __float2bfloat16(v - hf);
}

// ---------------- GEMM: hid[m][n] = sum_k A[m][k]*B[n][k] + bias[n] -----------
// split-bf16 3-term MFMA, 128x128 tile, BK=32, global_load_lds staging.
// Term-major MFMA order: each acc reused at distance 16 -> pipelined (no
// dependent 3-chain on the same accumulator).
__global__ __launch_bounds__(256, 3) void gemm_mfma(const __hip_bfloat16* __restrict__ Ahi,
                                                    const __hip_bfloat16* __restrict__ Alo,
                                                    const __hip_bfloat16* __restrict__ Bhi,
                                                    const __hip_bfloat16* __restrict__ Blo,
                                                    const float* __restrict__ bias,
                                                    float* __restrict__ hid, int r0) {
    __shared__ unsigned short Ah[128 * 32], Al[128 * 32], Bh[128 * 32], Bl[128 * 32];
    const int tid = threadIdx.x;
    const int lane = tid & 63;
    const int wave = tid >> 6;

    // bijective XCD tile swizzle: nwg = gx*gy is always a multiple of 8 here
    const int gx = gridDim.x;
    int fid = blockIdx.y * gx + blockIdx.x;
    const int per = (gx * gridDim.y) >> 3;
    fid = (fid & 7) * per + (fid >> 3);
    const int bm = (fid % gx) * 128;            // chunk-local m tile
    const int bn = (fid / gx) * 128;            // n tile

    const int wm = (wave & 1) * 64;
    const int wn = (wave >> 1) * 64;
    const int lm = lane & 15;                   // row within 16
    const int sl = (((lane >> 4) ^ (lm & 3)) << 3);   // swizzled k-octet (shorts)

    f32x4 acc[4][4];
#pragma unroll
    for (int i = 0; i < 4; ++i)
#pragma unroll
        for (int j = 0; j < 4; ++j) acc[i][j] = (f32x4){0.f, 0.f, 0.f, 0.f};

    for (int k0 = 0; k0 < Kdim; k0 += 32) {
        __syncthreads();
#pragma unroll
        for (int t = 0; t < 2; ++t) {
            const int c = tid + t * 256;        // 0..511; LDS dest byte = c*16 (linear)
            const int row = c >> 2;             // 0..127
            const int ko = (((c & 3) ^ (row & 3)) << 3);   // pre-swizzled source octet
            const size_t ga = (size_t)(r0 + bm + row) * Kdim + k0 + ko;
            const size_t gb = (size_t)(bn + row) * Kdim + k0 + ko;
            GLD16(&Ah[c * 8], Ahi + ga);
            GLD16(&Al[c * 8], Alo + ga);
            GLD16(&Bh[c * 8], Bhi + gb);
            GLD16(&Bl[c * 8], Blo + gb);
        }
        __syncthreads();                        // drains vmcnt (staging complete)

        bf16x8 ah[4], al[4], bh[4], bl[4];
#pragma unroll
        for (int i = 0; i < 4; ++i) {
            ah[i] = *(const bf16x8*)&Ah[(wm + i * 16 + lm) * 32 + sl];
            al[i] = *(const bf16x8*)&Al[(wm + i * 16 + lm) * 32 + sl];
            bh[i] = *(const bf16x8*)&Bh[(wn + i * 16 + lm) * 32 + sl];
            bl[i] = *(const bf16x8*)&Bl[(wn + i * 16 + lm) * 32 + sl];
        }
        // term-major: 16 independent MFMAs per term; acc reuse distance = 16
#pragma unroll
        for (int j = 0; j < 4; ++j)
#pragma unroll
            for (int i = 0; i < 4; ++i)
                acc[i][j] = __builtin_amdgcn_mfma_f32_16x16x32_bf16(ah[i], bh[j], acc[i][j], 0, 0, 0);
#pragma unroll
        for (int j = 0; j < 4; ++j)
#pragma unroll
            for (int i = 0; i < 4; ++i)
                acc[i][j] = __builtin_amdgcn_mfma_f32_16x16x32_bf16(ah[i], bl[j], acc[i][j], 0, 0, 0);
#pragma unroll
        for (int j = 0; j < 4; ++j)
#pragma unroll
            for (int i = 0; i < 4; ++i)
                acc[i][j] = __builtin_amdgcn_mfma_f32_16x16x32_bf16(al[i], bh[j], acc[i][j], 0, 0, 0);
    }

    // epilogue: C/D layout col=lane&15, row=(lane>>4)*4+reg  [m89/m91 verified]
    const int rbase = (lane >> 4) * 4;
#pragma unroll
    for (int j = 0; j < 4; ++j) {
        const int n = bn + wn + j * 16 + lm;
        const float bj = bias[n];
#pragma unroll
        for (int i = 0; i < 4; ++i) {
            const int m0 = bm + wm + i * 16 + rbase;
#pragma unroll
            for (int r2 = 0; r2 < 4; ++r2)
                hid[(size_t)(m0 + r2) * Ncols + n] = acc[i][j][r2] + bj;
        }
    }
}

// ---------------- Phase 2: per-wave online softmax -----------------------------
// One WAVE owns one (row, g): zero barriers, zero LDS, fully independent waves.
// Online noisy softmax with branchless rescale (exp(0)=1 exact => no-op when max
// doesn't grow). s2 accumulated in the noisy-max frame via s2 += p*inner
// (p*inner = exp(h - m1)). Outputs per row: codevectors, argmax, (M, 1/S2) for
// the marginal kernel. u read nontemporally (one-shot stream; keep hid in L3).
__global__ __launch_bounds__(256, 4) void phase2(const float* __restrict__ hid,
                                                 const float* __restrict__ u,
                                                 const float* __restrict__ emb,
                                                 float* __restrict__ mrow,
                                                 float* __restrict__ out,
                                                 int r0) {
    const int tid = threadIdx.x;
    const int lane = tid & 63;
    const int wid = tid >> 6;
    const int n = r0 + blockIdx.x * 4 + wid;
    const int g = blockIdx.y;

    const float* hrow = hid + (size_t)(n - r0) * Ncols + (size_t)g * Vsz;
    const float* urow = u + ((size_t)n * 2 + g) * Vsz;
    const float* embg = emb + (size_t)g * Vsz * 8;

    float m1 = -INFINITY, s1 = 0.f, s2 = 0.f, bestl = -INFINITY;
    int besti = 0;
    float cv[8];
#pragma unroll
    for (int d2 = 0; d2 < 8; ++d2) cv[d2] = 0.f;

    float h0[8], u0[8], h1[8], u1[8];
#pragma unroll
    for (int k = 0; k < 8; ++k) {
        h0[k] = hrow[k * 64 + lane];
        u0[k] = __builtin_nontemporal_load(urow + k * 64 + lane);
    }

#define CHUNK(CH, CU, NH, NU, c) {                                                 \
    if ((c) + 1 < 16) {   /* prefetch next chunk */                                \
        const int vb = ((c) + 1) * 512 + lane;                                     \
        _Pragma("unroll")                                                          \
        for (int k = 0; k < 8; ++k) {                                              \
            NH[k] = hrow[vb + k * 64];                                             \
            NU[k] = __builtin_nontemporal_load(urow + vb + k * 64);                \
        }                                                                          \
    }                                                                              \
    float l[8], inn[8];                                                            \
    float cmax = -INFINITY;                                                        \
    _Pragma("unroll")                                                              \
    for (int k = 0; k < 8; ++k) {                                                  \
        const float h = CH[k];                                                     \
        float uu = fminf(fmaxf(CU[k], 1.17549435e-38f), 1.0f);                     \
        const float d = uu - 1.0f;                                                 \
        float q = 1.0f / 9.0f;                                                     \
        q = fmaf(q, d, -0.125f);                                                   \
        q = fmaf(q, d, 1.0f / 7.0f);                                               \
        q = fmaf(q, d, -1.0f / 6.0f);                                              \
        q = fmaf(q, d, 0.2f);                                                      \
        q = fmaf(q, d, -0.25f);                                                    \
        q = fmaf(q, d, 1.0f / 3.0f);                                               \
        q = fmaf(q, d, -0.5f);                                                     \
        q = fmaf(q, d, 1.0f);                                                      \
        const float inner = (d > -0.2f) ? (-d) * q : -__logf(uu);                  \
        const float L = h - __logf(inner);                                         \
        l[k] = L; inn[k] = inner;                                                  \
        cmax = fmaxf(cmax, L);                                                     \
    }                                                                              \
    const float newm = fmaxf(m1, cmax);                                            \
    const float sc = __expf(m1 - newm);   /* ==1.0 exactly when max unchanged */   \
    m1 = newm;                                                                     \
    s1 *= sc; s2 *= sc;                                                            \
    _Pragma("unroll")                                                              \
    for (int d2 = 0; d2 < 8; ++d2) cv[d2] *= sc;                                   \
    _Pragma("unroll")                                                              \
    for (int k = 0; k < 8; ++k) {                                                  \
        const float p = __expf(l[k] - m1);                                         \
        s1 += p;                                                                   \
        s2 = fmaf(p, inn[k], s2);         /* p*inner = exp(h - m1) */              \
        const int v = (c) * 512 + k * 64 + lane;                                   \
        const float4 e0 = *(const float4*)(embg + (size_t)v * 8);                  \
        const float4 e1 = *(const float4*)(embg + (size_t)v * 8 + 4);              \
        cv[0] = fmaf(p, e0.x, cv[0]); cv[1] = fmaf(p, e0.y, cv[1]);                \
        cv[2] = fmaf(p, e0.z, cv[2]); cv[3] = fmaf(p, e0.w, cv[3]);                \
        cv[4] = fmaf(p, e1.x, cv[4]); cv[5] = fmaf(p, e1.y, cv[5]);                \
        cv[6] = fmaf(p, e1.z, cv[6]); cv[7] = fmaf(p, e1.w, cv[7]);                \
        if (l[k] > bestl) { bestl = l[k]; besti = v; }                             \
    }                                                                              \
}

#pragma unroll
    for (int c = 0; c < 16; c += 2) {
        CHUNK(h0, u0, h1, u1, c)
        CHUNK(h1, u1, h0, u0, c + 1)
    }
#undef CHUNK

    // ---- wave reduce (butterfly: totals on all lanes) ----
    float M = m1;
#pragma unroll
    for (int off = 32; off > 0; off >>= 1) M = fmaxf(M, __shfl_xor(M, off));
    const float scf = __expf(m1 - M);
    s1 *= scf; s2 *= scf;
#pragma unroll
    for (int d2 = 0; d2 < 8; ++d2) cv[d2] *= scf;
#pragma unroll
    for (int off = 32; off > 0; off >>= 1) {
        s1 += __shfl_xor(s1, off);
        s2 += __shfl_xor(s2, off);
    }
#pragma unroll
    for (int d2 = 0; d2 < 8; ++d2)
#pragma unroll
        for (int off = 32; off > 0; off >>= 1) cv[d2] += __shfl_xor(cv[d2], off);
#pragma unroll
    for (int off = 32; off > 0; off >>= 1) {
        const float ov = __shfl_xor(bestl, off);
        const int oi = __shfl_xor(besti, off);
        if (ov > bestl || (ov == bestl && oi < besti)) { bestl = ov; besti = oi; }
    }

    if (lane == 0) {
#pragma unroll
        for (int d2 = 0; d2 < 8; ++d2)
            out[(size_t)n * 16 + g * 8 + d2] = cv[d2] / s1;
        out[65537 + (size_t)n * 2 + g] = (float)besti;
        mrow[((size_t)n * 2 + g) * 2 + 0] = M;
        mrow[((size_t)n * 2 + g) * 2 + 1] = 1.0f / s2;
    }
}

// ---------------- marginal accumulate: softmax_clean summed over rows ----------
// block: 256 v-lanes x one (seg, g); loops its 256-row segment. hid from L3.
__global__ __launch_bounds__(256) void marg_acc(const float* __restrict__ hid,
                                                const float* __restrict__ mrow,
                                                const int* __restrict__ mask,
                                                float* __restrict__ part) {
    const int v = blockIdx.x * 256 + threadIdx.x;
    const int seg = blockIdx.y;
    const int g = blockIdx.z;
    const float* hp = hid + (size_t)g * Vsz + v;
    const int nbeg = seg * (Mrows / NSEG);

    float a0 = 0.f, a1 = 0.f, a2 = 0.f, a3 = 0.f;
    for (int n = nbeg; n < nbeg + Mrows / NSEG; n += 4) {
#pragma unroll
        for (int q2 = 0; q2 < 4; ++q2) {
            const int nn = n + q2;
            const float M = mrow[((size_t)nn * 2 + g) * 2 + 0];
            const float is2 = mrow[((size_t)nn * 2 + g) * 2 + 1];
            const float sc = mask[nn] ? is2 : 0.f;
            const float e = __expf(hp[(size_t)nn * Ncols] - M);
            if (q2 == 0) a0 = fmaf(e, sc, a0);
            else if (q2 == 1) a1 = fmaf(e, sc, a1);
            else if (q2 == 2) a2 = fmaf(e, sc, a2);
            else a3 = fmaf(e, sc, a3);
        }
    }
    part[((size_t)seg * 2 + g) * Vsz + v] = (a0 + a1) + (a2 + a3);
}

// ---------------- marginal reduce over segments --------------------------------
__global__ __launch_bounds__(256) void reduce_marg(const float* __restrict__ part,
                                                   float* __restrict__ marginal) {
    const int g = blockIdx.y;
    const int v = blockIdx.x * 256 + threadIdx.x;
    float s = 0.f;
    for (int b = 0; b < NSEG; ++b) s += part[((size_t)b * 2 + g) * Vsz + v];
    marginal[g * Vsz + v] = s;
}

// ---------------- Perplexity --------------------------------------------------
__global__ __launch_bounds__(256) void ppl_kernel(const float* __restrict__ marginal,
                                                  const int* __restrict__ mask,
                                                  float* __restrict__ out) {
    const int tid = threadIdx.x;
    const int lane = tid & 63;
    const int wid = tid >> 6;
    __shared__ float red[4];
    __shared__ int redi[4];

    int ms = 0;
    for (int i = tid; i < Mrows; i += 256) ms += mask[i];
#pragma unroll
    for (int off = 32; off > 0; off >>= 1) ms += __shfl_down(ms, off);
    if (lane == 0) redi[wid] = ms;
    __syncthreads();
    const float inv = 1.0f / (float)(redi[0] + redi[1] + redi[2] + redi[3]);

    float ppl = 0.f;
    for (int g = 0; g < 2; ++g) {
        float part = 0.f;
        for (int v = tid; v < Vsz; v += 256) {
            const float m = marginal[g * Vsz + v] * inv;
            part += m * logf(m + 1e-7f);
        }
#pragma unroll
        for (int off = 32; off > 0; off >>= 1) part += __shfl_down(part, off);
        __syncthreads();
        if (lane == 0) red[wid] = part;
        __syncthreads();
        if (tid == 0) ppl += __expf(-(red[0] + red[1] + red[2] + red[3]));
        __syncthreads();
    }
    if (tid == 0) out[65536] = ppl;
}

// ---------------- Launch ------------------------------------------------------
extern "C" void kernel_launch(void* const* d_in, const int* in_sizes, int n_in,
                              void* d_out, int out_size, void* d_ws, size_t ws_size,
                              hipStream_t stream) {
    const float* x    = (const float*)d_in[0];
    const float* u    = (const float*)d_in[1];
    const float* emb  = (const float*)d_in[2];
    const float* w    = (const float*)d_in[3];
    const float* bias = (const float*)d_in[4];
    const int*   mask = (const int*)d_in[5];
    float* out = (float*)d_out;

    char* base = (char*)d_ws;
    float* marginal = (float*)base;                                    // 64 KB
    float* mrow = (float*)(base + 65536);                              // 64 KB
    float* part = (float*)(base + 131072);                             // 1 MB
    __hip_bfloat16* Ahi = (__hip_bfloat16*)(base + 1179648);           // 2 MB
    __hip_bfloat16* Alo = Ahi + 1048576;                               // 2 MB
    __hip_bfloat16* Bhi = Alo + 1048576;                               // 8 MB
    __hip_bfloat16* Blo = Bhi + 4194304;                               // 8 MB
    const size_t hid_off = 1179648 + 4194304 + 16777216;               // ~22.2 MB
    float* hid = (float*)(base + hid_off);

    split_bf16<<<4096, 256, 0, stream>>>(x, Ahi, Alo);      // 1M elems
    split_bf16<<<16384, 256, 0, stream>>>(w, Bhi, Blo);     // 4M elems

    dim3 gg(Mrows / 128, Ncols / 128);
    gemm_mfma<<<gg, 256, 0, stream>>>(Ahi, Alo, Bhi, Blo, bias, hid, 0);
    dim3 pg(Mrows / 4, 2);
    phase2<<<pg, 256, 0, stream>>>(hid, u, emb, mrow, out, 0);

    marg_acc<<<dim3(Vsz / 256, NSEG, 2), 256, 0, stream>>>(hid, mrow, mask, part);
    reduce_marg<<<dim3(Vsz / 256, 2), 256, 0, stream>>>(part, marginal);
    ppl_kernel<<<1, 256, 0, stream>>>(marginal, mask, out);
}